// Round 10
// baseline (62.572 us; speedup 1.0000x reference)
//
#include <hip/hip_runtime.h>
#include <hip/hip_bf16.h>

#define N 8192
#define D 256
#define SP 8
#define NCHK 32                // 32 chunks of 16 cols = 512 cols per wave
#define LOG2E 1.44269504088896f

typedef __bf16 bf16x8 __attribute__((ext_vector_type(8)));
typedef float f32x4 __attribute__((ext_vector_type(4)));

static __device__ __forceinline__ unsigned short f2bf(float x) {
    union { float f; unsigned int u; } c; c.f = x;
    unsigned int r = (c.u + 0x7fffu + ((c.u >> 16) & 1u)) >> 16;
    return (unsigned short)r;
}

static __device__ __forceinline__ void gll16(const void* g, void* l) {
    __builtin_amdgcn_global_load_lds(
        (const __attribute__((address_space(1))) void*)g,
        (__attribute__((address_space(3))) void*)l, 16, 0, 0);
}

#define WAIT_VM8  asm volatile("s_waitcnt vmcnt(8)" ::: "memory")
#define WAIT_VM0  asm volatile("s_waitcnt vmcnt(0)" ::: "memory")
#define WAIT_LG0  asm volatile("s_waitcnt lgkmcnt(0)" ::: "memory")
#define SCHED0    __builtin_amdgcn_sched_barrier(0)

// ---------- kernel 1: norms + exact fp32 diag + normalized bf16 copies ----------
// A: linear, scaled by log2(e)/||a||  (so GEMM result = log2(e)*cos -> exp2 = e^cos)
// B: 512B rows, 32 chunks of 16B, chunk c -> c ^ (r&31) XOR pre-swizzle, scaled 1/||b||
__global__ __launch_bounds__(256) void conv_k(const float* __restrict__ o1,
                                              const float* __restrict__ o2,
                                              unsigned char* __restrict__ a_bf,
                                              unsigned char* __restrict__ b_bf,
                                              float* __restrict__ diag) {
    const int wid = threadIdx.x >> 6, lane = threadIdx.x & 63;
    const int r = blockIdx.x * 4 + wid;
    const float4* p1 = (const float4*)(o1 + (size_t)r * D);
    const float4* p2 = (const float4*)(o2 + (size_t)r * D);
    float4 v1 = p1[lane], v2 = p2[lane];
    float s1 = v1.x*v1.x + v1.y*v1.y + v1.z*v1.z + v1.w*v1.w;
    float s2 = v2.x*v2.x + v2.y*v2.y + v2.z*v2.z + v2.w*v2.w;
    float sd = v1.x*v2.x + v1.y*v2.y + v1.z*v2.z + v1.w*v2.w;
    #pragma unroll
    for (int m = 1; m < 64; m <<= 1) {
        s1 += __shfl_xor(s1, m);
        s2 += __shfl_xor(s2, m);
        sd += __shfl_xor(sd, m);
    }
    float i1 = 1.0f / sqrtf(s1);
    float i2 = 1.0f / sqrtf(s2);
    if (lane == 0) diag[r] = sd * i1 * i2;

    float a_sc = i1 * LOG2E;
    {   // A linear, log2e-scaled
        unsigned int lo = (unsigned int)f2bf(v1.x * a_sc) | ((unsigned int)f2bf(v1.y * a_sc) << 16);
        unsigned int hi = (unsigned int)f2bf(v1.z * a_sc) | ((unsigned int)f2bf(v1.w * a_sc) << 16);
        uint2 q; q.x = lo; q.y = hi;
        *(uint2*)(a_bf + (size_t)r * 512 + lane * 8) = q;
    }
    {   // B swizzled
        unsigned int lo = (unsigned int)f2bf(v2.x * i2) | ((unsigned int)f2bf(v2.y * i2) << 16);
        unsigned int hi = (unsigned int)f2bf(v2.z * i2) | ((unsigned int)f2bf(v2.w * i2) << 16);
        int c  = lane >> 1;
        int cs = c ^ (r & 31);
        uint2 q; q.x = lo; q.y = hi;
        *(uint2*)(b_bf + (size_t)r * 512 + cs * 16 + (lane & 1) * 8) = q;
    }
}

// ---------- kernel 2: barrier-free wave-private streaming GEMM + sum(exp) ----------
// block: 128 rows x 1024 cols; 4 waves = 2 row-waves x 2 col-halves
// wave: 64 rows x 512 cols, streamed as 32 chunks of 16 cols (full K per chunk)
// wave-private LDS: 2 x 8 KB buffers; sync = per-wave counted vmcnt ONLY.
__global__ __launch_bounds__(256, 2) void gemm9(const unsigned char* __restrict__ a_bf,
                                                const unsigned char* __restrict__ b_bf,
                                                float* __restrict__ s_part) {
    __shared__ __align__(16) unsigned char bls[4][16384];   // 64 KB: 16 KB per wave
    __shared__ float red[2][128];                           // 1 KB

    const int tid = threadIdx.x;
    const int lane = tid & 63, wid = tid >> 6;
    const int wrow = wid >> 1, ch = wid & 1;        // 2 row-waves x 2 col-halves
    const int l15 = lane & 15, lk = lane >> 4;      // lk = k-group 0..3
    const int bid = blockIdx.x;
    const int panel = bid & 7, rb = bid >> 3;       // 8 XCD-pinned panels x 64 row-blocks

    const unsigned char* aG = a_bf + (size_t)(rb * 128 + wrow * 64) * 512;
    const unsigned char* bG = b_bf + (size_t)(panel * 1024 + ch * 512) * 512;
    unsigned char* myl = bls[wid];                  // private 16 KB slice

    // A fragments in registers: rows mr*16 + l15 (of my 64), k-bytes ks*64 + lk*16
    bf16x8 af[4][8];
    #pragma unroll
    for (int mr = 0; mr < 4; ++mr)
        #pragma unroll
        for (int ks = 0; ks < 8; ++ks)
            af[mr][ks] = *(const bf16x8*)(aG + (size_t)(mr * 16 + l15) * 512
                                             + ks * 64 + lk * 16);

    // stage chunk c (16 cols x 512B = 8 KB) into buffer b; per-wave linear copy
#define STAGE(c, b)                                                             \
    {                                                                           \
        const unsigned char* src_ = bG + (size_t)(c) * 8192;                    \
        unsigned char* dst_ = myl + (b) * 8192;                                 \
        _Pragma("unroll")                                                       \
        for (int it = 0; it < 8; ++it) {                                        \
            int x_ = it * 1024 + lane * 16;                                     \
            gll16(src_ + x_, dst_ + x_);                                        \
        }                                                                       \
    }

    STAGE(0, 0);
    STAGE(1, 1);

    float srow[4][4];
    #pragma unroll
    for (int mr = 0; mr < 4; ++mr)
        #pragma unroll
        for (int rg = 0; rg < 4; ++rg) srow[mr][rg] = 0.f;

    #pragma unroll 1
    for (int p = 0; p < NCHK; ++p) {
        // my chunk-p loads are the oldest in my queue; newest 8 = chunk p+1
        if (p < NCHK - 1) { WAIT_VM8; } else { WAIT_VM0; }
        SCHED0;

        const unsigned char* cb = myl + (p & 1) * 8192;
        const int key = (p & 1) * 16 + l15;          // global col & 31
        bf16x8 bb[8];
        #pragma unroll
        for (int ks = 0; ks < 8; ++ks) {
            const int cs = (ks * 4 + lk) ^ key;
            bb[ks] = *(const bf16x8*)(cb + l15 * 512 + cs * 16);
        }
        WAIT_LG0;         // my reads retired -> safe to overwrite this buffer
        SCHED0;
        if (p + 2 < NCHK) STAGE(p + 2, p & 1);
        SCHED0;

        f32x4 acc[4];
        #pragma unroll
        for (int mr = 0; mr < 4; ++mr) acc[mr] = (f32x4){0.f, 0.f, 0.f, 0.f};

        __builtin_amdgcn_s_setprio(1);
        #pragma unroll
        for (int ks = 0; ks < 8; ++ks)
            #pragma unroll
            for (int mr = 0; mr < 4; ++mr)
                acc[mr] = __builtin_amdgcn_mfma_f32_16x16x32_bf16(
                    af[mr][ks], bb[ks], acc[mr], 0, 0, 0);
        __builtin_amdgcn_s_setprio(0);

        // acc = log2(e)*cos  ->  exp2 = e^cos  (single v_exp_f32, no mul)
        #pragma unroll
        for (int mr = 0; mr < 4; ++mr)
            #pragma unroll
            for (int rg = 0; rg < 4; ++rg)
                srow[mr][rg] += exp2f(acc[mr][rg]);
    }
#undef STAGE

    // reduce across the 16 column-lanes (C layout: col = lane&15, row = lk*4+rg)
    #pragma unroll
    for (int mr = 0; mr < 4; ++mr)
        #pragma unroll
        for (int rg = 0; rg < 4; ++rg) {
            float v = srow[mr][rg];
            v += __shfl_xor(v, 1);
            v += __shfl_xor(v, 2);
            v += __shfl_xor(v, 4);
            v += __shfl_xor(v, 8);
            srow[mr][rg] = v;
        }
    if (l15 == 0) {
        #pragma unroll
        for (int mr = 0; mr < 4; ++mr)
            #pragma unroll
            for (int rg = 0; rg < 4; ++rg)
                red[ch][wrow * 64 + mr * 16 + lk * 4 + rg] = srow[mr][rg];
    }
    __syncthreads();          // the only block-wide sync in the kernel
    if (tid < 128) {
        s_part[(size_t)panel * N + rb * 128 + tid] = red[0][tid] + red[1][tid];
    }
}

// ---------- kernel 3: per-row loss ----------
__global__ __launch_bounds__(128) void rowloss3(const float* __restrict__ s_part,
                                                const float* __restrict__ diag,
                                                float* __restrict__ partial) {
    const int t = threadIdx.x, rb = blockIdx.x;
    float s = 0.f;
    #pragma unroll
    for (int sp = 0; sp < SP; ++sp)
        s += s_part[(size_t)sp * N + rb * 128 + t];
    float loss = logf(s) - diag[rb * 128 + t];
    #pragma unroll
    for (int m = 1; m < 64; m <<= 1) loss += __shfl_xor(loss, m);
    __shared__ float redl[2];
    if ((t & 63) == 0) redl[t >> 6] = loss;
    __syncthreads();
    if (t == 0) partial[rb] = redl[0] + redl[1];
}

// ---------- kernel 4: final mean ----------
__global__ __launch_bounds__(64) void final_k(const float* __restrict__ partial,
                                              float* __restrict__ out) {
    const int t = threadIdx.x;
    float v = partial[t];
    #pragma unroll
    for (int m = 1; m < 64; m <<= 1) v += __shfl_xor(v, m);
    if (t == 0) out[0] = v / (float)N;
}

extern "C" void kernel_launch(void* const* d_in, const int* in_sizes, int n_in,
                              void* d_out, int out_size, void* d_ws, size_t ws_size,
                              hipStream_t stream) {
    const float* o1 = (const float*)d_in[0];
    const float* o2 = (const float*)d_in[1];

    unsigned char* w = (unsigned char*)d_ws;
    unsigned char* a_bf = w;                                   // 4 MB
    unsigned char* b_bf = w + (size_t)4 * 1024 * 1024;         // 4 MB
    float* diag    = (float*)(w + (size_t)8 * 1024 * 1024);    // 32 KB
    float* s_part  = diag + N;                                 // SP*N = 256 KB
    float* partial = s_part + (size_t)SP * N;                  // 256 B

    conv_k<<<N / 4, 256, 0, stream>>>(o1, o2, a_bf, b_bf, diag);
    gemm9<<<512, 256, 0, stream>>>(a_bf, b_bf, s_part);
    rowloss3<<<N / 128, 128, 0, stream>>>(s_part, diag, partial);
    final_k<<<1, 64, 0, stream>>>(partial, (float*)d_out);
}

// Round 11
// 60.574 us; speedup vs baseline: 1.0330x; 1.0330x over previous
//
#include <hip/hip_runtime.h>
#include <hip/hip_bf16.h>

#define N 8192
#define D 256
#define SP 8
#define NCH 16                 // 16 chunks of 64 cols = 1024 cols per panel
#define LOG2E 1.44269504088896f

typedef __bf16 bf16x8 __attribute__((ext_vector_type(8)));
typedef float f32x4 __attribute__((ext_vector_type(4)));

static __device__ __forceinline__ unsigned short f2bf(float x) {
    union { float f; unsigned int u; } c; c.f = x;
    unsigned int r = (c.u + 0x7fffu + ((c.u >> 16) & 1u)) >> 16;
    return (unsigned short)r;
}

static __device__ __forceinline__ void gll16(const void* g, void* l) {
    __builtin_amdgcn_global_load_lds(
        (const __attribute__((address_space(1))) void*)g,
        (__attribute__((address_space(3))) void*)l, 16, 0, 0);
}

#define WAIT_VM0  asm volatile("s_waitcnt vmcnt(0)" ::: "memory")
#define WAIT_LG0  asm volatile("s_waitcnt lgkmcnt(0)" ::: "memory")
#define SBAR      __builtin_amdgcn_s_barrier()
#define SCHED0    __builtin_amdgcn_sched_barrier(0)

// ---------- kernel 1: norms + exact fp32 diag + normalized bf16 copies ----------
// A: linear, scaled by log2(e)/||a||  (GEMM result = log2(e)*cos -> exp2 = e^cos)
// B: 512B rows, 32 chunks of 16B, chunk c -> c ^ (r&31) XOR pre-swizzle
__global__ __launch_bounds__(256) void conv_k(const float* __restrict__ o1,
                                              const float* __restrict__ o2,
                                              unsigned char* __restrict__ a_bf,
                                              unsigned char* __restrict__ b_bf,
                                              float* __restrict__ diag) {
    const int wid = threadIdx.x >> 6, lane = threadIdx.x & 63;
    const int r = blockIdx.x * 4 + wid;
    const float4* p1 = (const float4*)(o1 + (size_t)r * D);
    const float4* p2 = (const float4*)(o2 + (size_t)r * D);
    float4 v1 = p1[lane], v2 = p2[lane];
    float s1 = v1.x*v1.x + v1.y*v1.y + v1.z*v1.z + v1.w*v1.w;
    float s2 = v2.x*v2.x + v2.y*v2.y + v2.z*v2.z + v2.w*v2.w;
    float sd = v1.x*v2.x + v1.y*v2.y + v1.z*v2.z + v1.w*v2.w;
    #pragma unroll
    for (int m = 1; m < 64; m <<= 1) {
        s1 += __shfl_xor(s1, m);
        s2 += __shfl_xor(s2, m);
        sd += __shfl_xor(sd, m);
    }
    float i1 = 1.0f / sqrtf(s1);
    float i2 = 1.0f / sqrtf(s2);
    if (lane == 0) diag[r] = sd * i1 * i2;

    float a_sc = i1 * LOG2E;
    {   // A linear, log2e-scaled
        unsigned int lo = (unsigned int)f2bf(v1.x * a_sc) | ((unsigned int)f2bf(v1.y * a_sc) << 16);
        unsigned int hi = (unsigned int)f2bf(v1.z * a_sc) | ((unsigned int)f2bf(v1.w * a_sc) << 16);
        uint2 q; q.x = lo; q.y = hi;
        *(uint2*)(a_bf + (size_t)r * 512 + lane * 8) = q;
    }
    {   // B swizzled
        unsigned int lo = (unsigned int)f2bf(v2.x * i2) | ((unsigned int)f2bf(v2.y * i2) << 16);
        unsigned int hi = (unsigned int)f2bf(v2.z * i2) | ((unsigned int)f2bf(v2.w * i2) << 16);
        int c  = lane >> 1;
        int cs = c ^ (r & 31);
        uint2 q; q.x = lo; q.y = hi;
        *(uint2*)(b_bf + (size_t)r * 512 + cs * 16 + (lane & 1) * 8) = q;
    }
}

// ---------- kernel 2: 8-phase-style fine-interleaved GEMM + sum(exp) ----------
// grid 256 = 1 block/CU; block = 8 waves (4 row x 2 col), tile 256 rows x 1024 cols
// B streams in 16 chunks of 64 cols, dbuf 2x32KB; chunk = 4 sub-phases of
// {4 ds_read + 1 gll16 -> SBAR -> lgkmcnt(0) -> 16 MFMA -> SBAR}
__global__ __launch_bounds__(512, 1) void gemm10(const unsigned char* __restrict__ a_bf,
                                                 const unsigned char* __restrict__ b_bf,
                                                 float* __restrict__ s_part) {
    __shared__ __align__(16) unsigned char bls[2][32768];   // 64 KB
    __shared__ float red[2][256];                           // 2 KB

    const int tid = threadIdx.x;
    const int lane = tid & 63, wid = tid >> 6;
    const int wr = wid >> 1, wc = wid & 1;          // 4 row-waves x 2 col-waves
    const int l15 = lane & 15, lk = lane >> 4;      // lk = k-group 0..3
    const int bid = blockIdx.x;
    const int panel = bid & 7, rb = bid >> 3;       // 8 XCD-pinned panels x 32 row-blocks

    const unsigned char* aG = a_bf + (size_t)rb * (256 * 512);
    const unsigned char* bG = b_bf + (size_t)panel * ((size_t)1024 * 512);

    // A fragments: rows wr*64 + mr*16 + l15, k-bytes ks*64 + lk*16 (full K=256)
    bf16x8 af[4][8];
    #pragma unroll
    for (int mr = 0; mr < 4; ++mr)
        #pragma unroll
        for (int ks = 0; ks < 8; ++ks)
            af[mr][ks] = *(const bf16x8*)(aG + (size_t)(wr * 64 + mr * 16 + l15) * 512
                                             + ks * 64 + lk * 16);

    // prologue: stage chunk 0 (64 cols x 512 B = 32 KB; 4 gll16 per thread)
    #pragma unroll
    for (int it = 0; it < 4; ++it) {
        int x = it * 8192 + tid * 16;
        gll16(bG + x, &bls[0][x]);
    }

    float srow[4][4];
    #pragma unroll
    for (int mr = 0; mr < 4; ++mr)
        #pragma unroll
        for (int rg = 0; rg < 4; ++rg) srow[mr][rg] = 0.f;

    int cur = 0;

    #pragma unroll 1
    for (int p = 0; p < NCH; ++p) {
        // chunk start: everyone's stage(p) landed (issued >=1 sub-phase ago, L2-hot)
        WAIT_VM0; SCHED0;
        SBAR;

        f32x4 acc[4][2];
        #pragma unroll
        for (int mr = 0; mr < 4; ++mr)
            #pragma unroll
            for (int nc = 0; nc < 2; ++nc)
                acc[mr][nc] = (f32x4){0.f, 0.f, 0.f, 0.f};

        const unsigned char* cb = bls[cur];
        unsigned char* nb = bls[cur ^ 1];

        #pragma unroll
        for (int q = 0; q < 4; ++q) {
            // sub-phase q: read bb for ks=2q,2q+1, stage 1/4 of chunk p+1
            bf16x8 bb[2][2];
            #pragma unroll
            for (int dk = 0; dk < 2; ++dk)
                #pragma unroll
                for (int nc = 0; nc < 2; ++nc) {
                    const int ks = 2 * q + dk;
                    const int col = wc * 32 + nc * 16 + l15;
                    const int cs = (ks * 4 + lk) ^ (col & 31);
                    bb[dk][nc] = *(const bf16x8*)(cb + col * 512 + cs * 16);
                }
            if (p < NCH - 1) {
                int x = q * 8192 + tid * 16;
                gll16(bG + (size_t)(p + 1) * 32768 + x, nb + x);
            }
            SBAR;                   // all waves issued reads/stage for this sub-phase
            WAIT_LG0; SCHED0;       // my 4 ds_reads landed (hid under barrier wait)
            __builtin_amdgcn_s_setprio(1);
            #pragma unroll
            for (int dk = 0; dk < 2; ++dk)
                #pragma unroll
                for (int nc = 0; nc < 2; ++nc)
                    #pragma unroll
                    for (int mr = 0; mr < 4; ++mr)
                        acc[mr][nc] = __builtin_amdgcn_mfma_f32_16x16x32_bf16(
                            af[mr][2 * q + dk], bb[dk][nc], acc[mr][nc], 0, 0, 0);
            __builtin_amdgcn_s_setprio(0);
            if (q < 3) SBAR;        // sub-phase 3 un-barriered: waves de-phase into exp
        }

        // acc = log2(e)*cos -> exp2 = e^cos (single v_exp_f32 each)
        #pragma unroll
        for (int mr = 0; mr < 4; ++mr)
            #pragma unroll
            for (int rg = 0; rg < 4; ++rg)
                srow[mr][rg] += exp2f(acc[mr][0][rg]) + exp2f(acc[mr][1][rg]);

        cur ^= 1;
    }

    // reduce across the 16 column-lanes (C layout: col = lane&15, row = lk*4+rg)
    #pragma unroll
    for (int mr = 0; mr < 4; ++mr)
        #pragma unroll
        for (int rg = 0; rg < 4; ++rg) {
            float v = srow[mr][rg];
            v += __shfl_xor(v, 1);
            v += __shfl_xor(v, 2);
            v += __shfl_xor(v, 4);
            v += __shfl_xor(v, 8);
            srow[mr][rg] = v;
        }
    if (l15 == 0) {
        #pragma unroll
        for (int mr = 0; mr < 4; ++mr)
            #pragma unroll
            for (int rg = 0; rg < 4; ++rg)
                red[wc][wr * 64 + mr * 16 + lk * 4 + rg] = srow[mr][rg];
    }
    __syncthreads();
    if (tid < 256) {
        s_part[(size_t)panel * N + rb * 256 + tid] = red[0][tid] + red[1][tid];
    }
}

// ---------- kernel 3: per-row loss ----------
__global__ __launch_bounds__(128) void rowloss3(const float* __restrict__ s_part,
                                                const float* __restrict__ diag,
                                                float* __restrict__ partial) {
    const int t = threadIdx.x, rb = blockIdx.x;
    float s = 0.f;
    #pragma unroll
    for (int sp = 0; sp < SP; ++sp)
        s += s_part[(size_t)sp * N + rb * 128 + t];
    float loss = logf(s) - diag[rb * 128 + t];
    #pragma unroll
    for (int m = 1; m < 64; m <<= 1) loss += __shfl_xor(loss, m);
    __shared__ float redl[2];
    if ((t & 63) == 0) redl[t >> 6] = loss;
    __syncthreads();
    if (t == 0) partial[rb] = redl[0] + redl[1];
}

// ---------- kernel 4: final mean ----------
__global__ __launch_bounds__(64) void final_k(const float* __restrict__ partial,
                                              float* __restrict__ out) {
    const int t = threadIdx.x;
    float v = partial[t];
    #pragma unroll
    for (int m = 1; m < 64; m <<= 1) v += __shfl_xor(v, m);
    if (t == 0) out[0] = v / (float)N;
}

extern "C" void kernel_launch(void* const* d_in, const int* in_sizes, int n_in,
                              void* d_out, int out_size, void* d_ws, size_t ws_size,
                              hipStream_t stream) {
    const float* o1 = (const float*)d_in[0];
    const float* o2 = (const float*)d_in[1];

    unsigned char* w = (unsigned char*)d_ws;
    unsigned char* a_bf = w;                                   // 4 MB
    unsigned char* b_bf = w + (size_t)4 * 1024 * 1024;         // 4 MB
    float* diag    = (float*)(w + (size_t)8 * 1024 * 1024);    // 32 KB
    float* s_part  = diag + N;                                 // SP*N = 256 KB
    float* partial = s_part + (size_t)SP * N;                  // 256 B

    conv_k<<<N / 4, 256, 0, stream>>>(o1, o2, a_bf, b_bf, diag);
    gemm10<<<256, 512, 0, stream>>>(a_bf, b_bf, s_part);
    rowloss3<<<N / 128, 128, 0, stream>>>(s_part, diag, partial);
    final_k<<<1, 64, 0, stream>>>(partial, (float*)d_out);
}

// Round 12
// 46.412 us; speedup vs baseline: 1.3482x; 1.3051x over previous
//
#include <hip/hip_runtime.h>
#include <hip/hip_bf16.h>

#define N 8192
#define D 256
#define SP 8
#define NCHK 16                // 16 chunks of 64 cols = 1024 cols per panel
#define LOG2E 1.44269504088896f

typedef int   i32x4 __attribute__((ext_vector_type(4)));
typedef int   i32x8 __attribute__((ext_vector_type(8)));
typedef float f32x4 __attribute__((ext_vector_type(4)));

static __device__ __forceinline__ void gll16(const void* g, void* l) {
    __builtin_amdgcn_global_load_lds(
        (const __attribute__((address_space(1))) void*)g,
        (__attribute__((address_space(3))) void*)l, 16, 0, 0);
}

#define WAIT_VM0  asm volatile("s_waitcnt vmcnt(0)" ::: "memory")
#define WAIT_LG0  asm volatile("s_waitcnt lgkmcnt(0)" ::: "memory")
#define SBAR      __builtin_amdgcn_s_barrier()
#define SCHED0    __builtin_amdgcn_sched_barrier(0)

// ---------- kernel 1: norms + exact fp32 diag + normalized fp8(e4m3) copies ----------
// A: linear 256B rows, scaled by log2(e)/||a||  (GEMM result = log2e*cos -> exp2)
// B: 256B rows, 16 chunks of 16B, chunk c -> c ^ (r&15) XOR pre-swizzle, scaled 1/||b||
__global__ __launch_bounds__(256) void conv_k(const float* __restrict__ o1,
                                              const float* __restrict__ o2,
                                              unsigned char* __restrict__ a8,
                                              unsigned char* __restrict__ b8,
                                              float* __restrict__ diag) {
    const int wid = threadIdx.x >> 6, lane = threadIdx.x & 63;
    const int r = blockIdx.x * 4 + wid;
    const float4* p1 = (const float4*)(o1 + (size_t)r * D);
    const float4* p2 = (const float4*)(o2 + (size_t)r * D);
    float4 v1 = p1[lane], v2 = p2[lane];
    float s1 = v1.x*v1.x + v1.y*v1.y + v1.z*v1.z + v1.w*v1.w;
    float s2 = v2.x*v2.x + v2.y*v2.y + v2.z*v2.z + v2.w*v2.w;
    float sd = v1.x*v2.x + v1.y*v2.y + v1.z*v2.z + v1.w*v2.w;
    #pragma unroll
    for (int m = 1; m < 64; m <<= 1) {
        s1 += __shfl_xor(s1, m);
        s2 += __shfl_xor(s2, m);
        sd += __shfl_xor(sd, m);
    }
    float i1 = 1.0f / sqrtf(s1);
    float i2 = 1.0f / sqrtf(s2);
    if (lane == 0) diag[r] = sd * i1 * i2;

    float a_sc = i1 * LOG2E;
    {   // A linear fp8: lane's 4 k-values -> 4 bytes at r*256 + lane*4
        int pa = __builtin_amdgcn_cvt_pk_fp8_f32(v1.x * a_sc, v1.y * a_sc, 0, false);
        pa     = __builtin_amdgcn_cvt_pk_fp8_f32(v1.z * a_sc, v1.w * a_sc, pa, true);
        *(int*)(a8 + (size_t)r * 256 + lane * 4) = pa;
    }
    {   // B swizzled fp8: 16B chunk c = lane>>2, stored at c ^ (r&15)
        int pb = __builtin_amdgcn_cvt_pk_fp8_f32(v2.x * i2, v2.y * i2, 0, false);
        pb     = __builtin_amdgcn_cvt_pk_fp8_f32(v2.z * i2, v2.w * i2, pb, true);
        int c  = lane >> 2;
        int cs = c ^ (r & 15);
        *(int*)(b8 + (size_t)r * 256 + cs * 16 + (lane & 3) * 4) = pb;
    }
}

// ---------- kernel 2: MX-fp8 K=128 GEMM (gemm8 structure) + row-wise sum(exp) ----------
// block: 128 rows x 1024 cols; 4 waves = 2 row x 2 col; wave tile 64 x 32
// per wave: af[4][2] i32x8 (64 regs), acc[4][2] (8 chains, depth 2); dbuf LDS 32 KB
__global__ __launch_bounds__(256, 2) void gemm11(const unsigned char* __restrict__ a8,
                                                 const unsigned char* __restrict__ b8,
                                                 float* __restrict__ s_part) {
    __shared__ __align__(16) unsigned char bls[2][16384];   // 32 KB
    __shared__ float red[2][128];                           // 1 KB

    const int tid = threadIdx.x;
    const int lane = tid & 63, wid = tid >> 6;
    const int wr = wid >> 1, wc = wid & 1;          // 2 row-waves x 2 col-waves
    const int l15 = lane & 15, lk = lane >> 4;      // lk = k-group 0..3
    const int bid = blockIdx.x;
    const int panel = bid & 7, rb = bid >> 3;       // 8 XCD-pinned panels x 64 row-blocks

    const unsigned char* aG = a8 + (size_t)rb * (128 * 256);
    const unsigned char* bG = b8 + (size_t)panel * ((size_t)1024 * 256);

    // A fragments: rows wr*64 + mr*16 + l15; k-bytes kh*128 + lk*32 (32B per frag)
    i32x8 af[4][2];
    #pragma unroll
    for (int mr = 0; mr < 4; ++mr)
        #pragma unroll
        for (int kh = 0; kh < 2; ++kh)
            af[mr][kh] = *(const i32x8*)(aG + (size_t)(wr * 64 + mr * 16 + l15) * 256
                                            + kh * 128 + lk * 32);

    // prologue: stage chunk 0 (64 cols x 256B = 16 KB; 4 x 16B per thread, linear)
    #pragma unroll
    for (int it = 0; it < 4; ++it) {
        int x = it * 4096 + tid * 16;
        gll16(bG + x, &bls[0][x]);
    }

    float srow[4][4];
    #pragma unroll
    for (int mr = 0; mr < 4; ++mr)
        #pragma unroll
        for (int rg = 0; rg < 4; ++rg) srow[mr][rg] = 0.f;

    int cur = 0;

    #pragma unroll 1
    for (int p = 0; p < NCHK; ++p) {
        WAIT_VM0;      // my stage(p) landed (issued a full phase ago; ~free)
        SCHED0;
        SBAR;          // everyone's stage(p) landed; buf[p-1] readers all done

        if (p < NCHK - 1) {
            const unsigned char* src = bG + (size_t)(p + 1) * 16384;
            unsigned char* dst = bls[cur ^ 1];
            #pragma unroll
            for (int it = 0; it < 4; ++it) {
                int x = it * 4096 + tid * 16;
                gll16(src + x, dst + x);
            }
        }

        f32x4 acc[4][2];
        #pragma unroll
        for (int mr = 0; mr < 4; ++mr)
            #pragma unroll
            for (int nc = 0; nc < 2; ++nc)
                acc[mr][nc] = (f32x4){0.f, 0.f, 0.f, 0.f};

        const unsigned char* cb = bls[cur];

        __builtin_amdgcn_s_setprio(1);
        #pragma unroll
        for (int kh = 0; kh < 2; ++kh) {
            i32x8 bb[2];
            #pragma unroll
            for (int nc = 0; nc < 2; ++nc) {
                const int col = wc * 32 + nc * 16 + l15;
                const int c0  = kh * 8 + lk * 2;        // 16B-chunk index of my 32B
                const int cs0 = c0 ^ l15;               // swizzle key = col&15 = l15
                i32x4 lo = *(const i32x4*)(cb + col * 256 + cs0 * 16);
                i32x4 hi = *(const i32x4*)(cb + col * 256 + (cs0 ^ 1) * 16);
                i32x8 b;
                b[0] = lo[0]; b[1] = lo[1]; b[2] = lo[2]; b[3] = lo[3];
                b[4] = hi[0]; b[5] = hi[1]; b[6] = hi[2]; b[7] = hi[3];
                bb[nc] = b;
            }
            #pragma unroll
            for (int nc = 0; nc < 2; ++nc)
                #pragma unroll
                for (int mr = 0; mr < 4; ++mr)
                    acc[mr][nc] = __builtin_amdgcn_mfma_scale_f32_16x16x128_f8f6f4(
                        af[mr][kh], bb[nc], acc[mr][nc],
                        0, 0,            // cbsz=FP8, blgp=FP8
                        0, 0x7F,         // scale A: opsel 0, E8M0 = 1.0
                        0, 0x7F);        // scale B: opsel 0, E8M0 = 1.0
        }
        __builtin_amdgcn_s_setprio(0);
        WAIT_LG0;      // my reads of cur retired (buffer reusable next phase)
        SCHED0;

        // acc = log2(e)*cos -> exp2 = e^cos (single v_exp_f32 each)
        #pragma unroll
        for (int mr = 0; mr < 4; ++mr)
            #pragma unroll
            for (int rg = 0; rg < 4; ++rg)
                srow[mr][rg] += exp2f(acc[mr][0][rg]) + exp2f(acc[mr][1][rg]);

        cur ^= 1;
    }

    // reduce across the 16 column-lanes (C layout: col = lane&15, row = lk*4+rg)
    #pragma unroll
    for (int mr = 0; mr < 4; ++mr)
        #pragma unroll
        for (int rg = 0; rg < 4; ++rg) {
            float v = srow[mr][rg];
            v += __shfl_xor(v, 1);
            v += __shfl_xor(v, 2);
            v += __shfl_xor(v, 4);
            v += __shfl_xor(v, 8);
            srow[mr][rg] = v;
        }
    if (l15 == 0) {
        #pragma unroll
        for (int mr = 0; mr < 4; ++mr)
            #pragma unroll
            for (int rg = 0; rg < 4; ++rg)
                red[wc][wr * 64 + mr * 16 + lk * 4 + rg] = srow[mr][rg];
    }
    __syncthreads();
    if (tid < 128) {
        s_part[(size_t)panel * N + rb * 128 + tid] = red[0][tid] + red[1][tid];
    }
}

// ---------- kernel 3: per-row loss ----------
__global__ __launch_bounds__(128) void rowloss3(const float* __restrict__ s_part,
                                                const float* __restrict__ diag,
                                                float* __restrict__ partial) {
    const int t = threadIdx.x, rb = blockIdx.x;
    float s = 0.f;
    #pragma unroll
    for (int sp = 0; sp < SP; ++sp)
        s += s_part[(size_t)sp * N + rb * 128 + t];
    float loss = logf(s) - diag[rb * 128 + t];
    #pragma unroll
    for (int m = 1; m < 64; m <<= 1) loss += __shfl_xor(loss, m);
    __shared__ float redl[2];
    if ((t & 63) == 0) redl[t >> 6] = loss;
    __syncthreads();
    if (t == 0) partial[rb] = redl[0] + redl[1];
}

// ---------- kernel 4: final mean ----------
__global__ __launch_bounds__(64) void final_k(const float* __restrict__ partial,
                                              float* __restrict__ out) {
    const int t = threadIdx.x;
    float v = partial[t];
    #pragma unroll
    for (int m = 1; m < 64; m <<= 1) v += __shfl_xor(v, m);
    if (t == 0) out[0] = v / (float)N;
}

extern "C" void kernel_launch(void* const* d_in, const int* in_sizes, int n_in,
                              void* d_out, int out_size, void* d_ws, size_t ws_size,
                              hipStream_t stream) {
    const float* o1 = (const float*)d_in[0];
    const float* o2 = (const float*)d_in[1];

    unsigned char* w = (unsigned char*)d_ws;
    unsigned char* a8 = w;                                     // 2 MB
    unsigned char* b8 = w + (size_t)2 * 1024 * 1024;           // 2 MB
    float* diag    = (float*)(w + (size_t)4 * 1024 * 1024);    // 32 KB
    float* s_part  = diag + N;                                 // SP*N = 256 KB
    float* partial = s_part + (size_t)SP * N;                  // 256 B

    conv_k<<<N / 4, 256, 0, stream>>>(o1, o2, a8, b8, diag);
    gemm11<<<512, 256, 0, stream>>>(a8, b8, s_part);
    rowloss3<<<N / 128, 128, 0, stream>>>(s_part, diag, partial);
    final_k<<<1, 64, 0, stream>>>(partial, (float*)d_out);
}